// Round 12
// baseline (246.649 us; speedup 1.0000x reference)
//
#include <hip/hip_runtime.h>
#include <cstdint>
#include <cstddef>

#define B_ 8
#define N_ 4096
#define C_ 512
#define KV_ 960
#define DQ 128
#define DK 240
#define NSPLIT 16  // split-K over n for k1; grid 32*16*2 = 1024 blocks = 4/CU

typedef __attribute__((ext_vector_type(8))) short bf16x8;
typedef __attribute__((ext_vector_type(4))) float f32x4;
#define AS1 __attribute__((address_space(1)))
#define AS3 __attribute__((address_space(3)))

__device__ __forceinline__ ushort f2bf(float f) {
  uint32_t u = __float_as_uint(f);
  u += 0x7FFFu + ((u >> 16) & 1u);  // RNE
  return (ushort)(u >> 16);
}

__device__ __forceinline__ uint32_t cvtpk(float lo, float hi) {
  uint32_t r;
  asm("v_cvt_pk_bf16_f32 %0, %1, %2" : "=v"(r) : "v"(lo), "v"(hi));
  return r;
}

union bfpack {
  uint32_t u[4];
  ushort s[8];
  bf16x8 v;
};

// ---------------------------------------------------------------------------
// K1 (MFMA, gather-staged, 4 blocks/CU): partial
//   S[b,h,i,j] = sum_{n in split} emb1[b,n,h*128+i] * embaBF[b,n,h*240+j]
// (R6-proven structure, NSPLIT=16; unchanged from R11)
// ---------------------------------------------------------------------------
__global__ __launch_bounds__(512) void k1_mfma(const float* __restrict__ emb1,
                                               const ushort* __restrict__ embaBF,
                                               float* __restrict__ P) {
  __shared__ ushort As[128 * 64];
  __shared__ ushort Bs[128 * 64];
  const int bh = blockIdx.x;
  const int split = blockIdx.y;
  const int jh = blockIdx.z;
  const int b = bh >> 2, h = bh & 3;
  const int t = threadIdx.x;
  const int w = t >> 6, l = t & 63;
  const int wm = w >> 1, wn = w & 1;

  const float* Abase = emb1 + (size_t)b * N_ * C_ + h * DQ;
  const ushort* Bbase = embaBF + (size_t)b * N_ * KV_;

  const int cA = t & 127;
  const int jB = t & 127;
  const int nb0 = t >> 7;
  int jl = jh * 128 + jB;
  if (jl > DK - 1) jl = DK - 1;
  const int jg = h * DK + jl;

  f32x4 acc[2][4];
#pragma unroll
  for (int fm = 0; fm < 2; ++fm)
#pragma unroll
    for (int fn = 0; fn < 4; ++fn) acc[fm][fn] = (f32x4){0.f, 0.f, 0.f, 0.f};

  const int n0 = split * (N_ / NSPLIT);
  const int lrow = l & 15;
  const int KS = (N_ / NSPLIT) / 64;  // 4

  float va[2][8];
  ushort ub[2][8];

#pragma unroll
  for (int q = 0; q < 2; ++q) {
    const float* g = Abase + (size_t)(n0 + (nb0 + q * 4) * 8) * C_ + cA;
#pragma unroll
    for (int kk = 0; kk < 8; ++kk) va[q][kk] = g[(size_t)kk * C_];
  }
#pragma unroll
  for (int q = 0; q < 2; ++q) {
    const ushort* g = Bbase + (size_t)(n0 + (nb0 + q * 4) * 8) * KV_ + jg;
#pragma unroll
    for (int kk = 0; kk < 8; ++kk) ub[q][kk] = g[(size_t)kk * KV_];
  }

  for (int ks = 0; ks < KS; ++ks) {
    bfpack pa[2], pb[2];
#pragma unroll
    for (int q = 0; q < 2; ++q)
#pragma unroll
      for (int p = 0; p < 4; ++p) pa[q].u[p] = cvtpk(va[q][2 * p], va[q][2 * p + 1]);
#pragma unroll
    for (int q = 0; q < 2; ++q)
#pragma unroll
      for (int kk = 0; kk < 8; ++kk) pb[q].s[kk] = ub[q][kk];

    __builtin_amdgcn_s_barrier();

#pragma unroll
    for (int q = 0; q < 2; ++q) {
      const int nb = nb0 + q * 4;
      *(bf16x8*)(As + cA * 64 + ((nb ^ (cA & 7)) << 3)) = pa[q].v;
      *(bf16x8*)(Bs + jB * 64 + ((nb ^ (jB & 7)) << 3)) = pb[q].v;
    }

    if (ks + 1 < KS) {
      const int nb1 = n0 + (ks + 1) * 64;
#pragma unroll
      for (int q = 0; q < 2; ++q) {
        const float* g = Abase + (size_t)(nb1 + (nb0 + q * 4) * 8) * C_ + cA;
#pragma unroll
        for (int kk = 0; kk < 8; ++kk) va[q][kk] = g[(size_t)kk * C_];
      }
#pragma unroll
      for (int q = 0; q < 2; ++q) {
        const ushort* g = Bbase + (size_t)(nb1 + (nb0 + q * 4) * 8) * KV_ + jg;
#pragma unroll
        for (int kk = 0; kk < 8; ++kk) ub[q][kk] = g[(size_t)kk * KV_];
      }
    }

    asm volatile("s_waitcnt lgkmcnt(0)" ::: "memory");
    __builtin_amdgcn_sched_barrier(0);
    __builtin_amdgcn_s_barrier();

#pragma unroll
    for (int half = 0; half < 2; ++half) {
      const int kb = half * 4 + (l >> 4);
      bf16x8 af[2], bv[4];
#pragma unroll
      for (int fm = 0; fm < 2; ++fm) {
        const int i = wm * 32 + fm * 16 + lrow;
        af[fm] = *(const bf16x8*)(As + i * 64 + ((kb ^ (i & 7)) << 3));
      }
#pragma unroll
      for (int fn = 0; fn < 4; ++fn) {
        const int j = wn * 64 + fn * 16 + lrow;
        bv[fn] = *(const bf16x8*)(Bs + j * 64 + ((kb ^ (j & 7)) << 3));
      }
#pragma unroll
      for (int fm = 0; fm < 2; ++fm)
#pragma unroll
        for (int fn = 0; fn < 4; ++fn)
          acc[fm][fn] = __builtin_amdgcn_mfma_f32_16x16x32_bf16(af[fm], bv[fn],
                                                                acc[fm][fn], 0, 0, 0);
    }
  }
  f32x4* Pv4 = (f32x4*)P + ((size_t)(split * 32 + bh) * 2 + jh) * 4096;
#pragma unroll
  for (int fm = 0; fm < 2; ++fm)
#pragma unroll
    for (int fn = 0; fn < 4; ++fn) Pv4[(fm * 4 + fn) * 512 + t] = acc[fm][fn];
}

// ---------------------------------------------------------------------------
// Reduce NSPLIT fragment-native partials and un-swizzle into S[bh][128][240].
// ---------------------------------------------------------------------------
__global__ __launch_bounds__(256) void k_reduce_frag(const f32x4* __restrict__ P,
                                                     float* __restrict__ S) {
  const int bh = blockIdx.x;
  const int g = blockIdx.y * 256 + threadIdx.x;
  const int jh = g >> 12;
  const int rest = g & 4095;
  f32x4 a = P[((size_t)bh * 2 + jh) * 4096 + rest];
#pragma unroll
  for (int s = 1; s < NSPLIT; ++s) {
    f32x4 v = P[((size_t)(s * 32 + bh) * 2 + jh) * 4096 + rest];
    a.x += v.x; a.y += v.y; a.z += v.z; a.w += v.w;
  }
  const int v = rest >> 9, tt = rest & 511;
  const int fm = v >> 2, fn = v & 3;
  const int wv = tt >> 6, l = tt & 63;
  const int wm = wv >> 1, wn = wv & 1;
  const int i0 = wm * 32 + fm * 16 + (l >> 4) * 4;
  const int j = jh * 128 + wn * 64 + fn * 16 + (l & 15);
  if (j < DK) {
    float* sp = S + (size_t)bh * (DQ * DK) + (size_t)i0 * DK + j;
    sp[0] = a.x; sp[DK] = a.y; sp[2 * DK] = a.z; sp[3 * DK] = a.w;
  }
}

// ---------------------------------------------------------------------------
// f32 -> bf16 (RNE), 4 elems/thread
// ---------------------------------------------------------------------------
__global__ __launch_bounds__(256) void k_cvt(const float4* __restrict__ in,
                                             ushort4* __restrict__ out, int n4) {
  int i = blockIdx.x * 256 + threadIdx.x;
  if (i >= n4) return;
  float4 v = in[i];
  ushort4 o;
  o.x = f2bf(v.x); o.y = f2bf(v.y); o.z = f2bf(v.z); o.w = f2bf(v.w);
  out[i] = o;
}

// ===========================================================================
// Flat-batched f32 chain GEMMs (unchanged from R6).
// ===========================================================================
__global__ __launch_bounds__(256) void k_g1(const float* __restrict__ Wq,
                                            const float* __restrict__ S,
                                            float* __restrict__ U) {
  const int h = blockIdx.x, c0 = blockIdx.y * 64;
  const int b = blockIdx.z / 5, n0 = (blockIdx.z % 5) * 48;
  const float* A = Wq + (size_t)h * 16384;
  const float* Bp = S + (size_t)(b * 4 + h) * 30720 + n0;
  float* Cp = U + (size_t)(b * 4 + h) * 30720 + n0;
  __shared__ float Ast[16][65];
  __shared__ float Bst[16][49];
  const int t = threadIdx.x;
  const int mi = (t >> 4) * 4, nj = (t & 15) * 3;
  float acc[4][3] = {};
  for (int k0 = 0; k0 < 128; k0 += 16) {
    __syncthreads();
#pragma unroll
    for (int q = 0; q < 4; ++q) {
      int idx = t + q * 256, m = idx >> 4, k = idx & 15;
      Ast[k][m] = A[(size_t)(c0 + m) * 128 + k0 + k];
    }
#pragma unroll
    for (int q = 0; q < 3; ++q) {
      int idx = t + q * 256, k = idx / 48, n = idx % 48;
      Bst[k][n] = Bp[(size_t)(k0 + k) * 240 + n];
    }
    __syncthreads();
#pragma unroll
    for (int kk = 0; kk < 16; ++kk) {
      float a4[4], b3[3];
#pragma unroll
      for (int x = 0; x < 4; ++x) a4[x] = Ast[kk][mi + x];
#pragma unroll
      for (int y = 0; y < 3; ++y) b3[y] = Bst[kk][nj + y];
#pragma unroll
      for (int x = 0; x < 4; ++x)
#pragma unroll
        for (int y = 0; y < 3; ++y) acc[x][y] = fmaf(a4[x], b3[y], acc[x][y]);
    }
  }
#pragma unroll
  for (int x = 0; x < 4; ++x)
#pragma unroll
    for (int y = 0; y < 3; ++y)
      Cp[(size_t)(c0 + mi + x) * 240 + nj + y] = acc[x][y];
}

__global__ __launch_bounds__(256) void k_g2(const float* __restrict__ U,
                                            const float* __restrict__ Wk,
                                            float* __restrict__ SC) {
  const int m0 = blockIdx.x * 64, n0 = blockIdx.y * 48;
  __shared__ float Ast[16][65];
  __shared__ float Bst2[48][17];
  const int t = threadIdx.x;
  const int mi = (t >> 4) * 4, nj = (t & 15) * 3;
  float acc[4][3] = {};
  for (int k0 = 0; k0 < 240; k0 += 16) {
    __syncthreads();
#pragma unroll
    for (int q = 0; q < 4; ++q) {
      int idx = t + q * 256, m = idx >> 4, k = idx & 15;
      Ast[k][m] = U[(size_t)(m0 + m) * 240 + k0 + k];
    }
#pragma unroll
    for (int q = 0; q < 3; ++q) {
      int idx = t + q * 256, n = idx >> 4, kd = idx & 15;
      Bst2[n][kd] = Wk[(size_t)(n0 + n) * 240 + k0 + kd];
    }
    __syncthreads();
#pragma unroll
    for (int kk = 0; kk < 16; ++kk) {
      float a4[4], b3[3];
#pragma unroll
      for (int x = 0; x < 4; ++x) a4[x] = Ast[kk][mi + x];
#pragma unroll
      for (int y = 0; y < 3; ++y) b3[y] = Bst2[nj + y][kk];
#pragma unroll
      for (int x = 0; x < 4; ++x)
#pragma unroll
        for (int y = 0; y < 3; ++y) acc[x][y] = fmaf(a4[x], b3[y], acc[x][y]);
    }
  }
  const float scale = 0.0322748612183951f;
#pragma unroll
  for (int x = 0; x < 4; ++x)
#pragma unroll
    for (int y = 0; y < 3; ++y)
      SC[(size_t)(m0 + mi + x) * 240 + n0 + nj + y] = acc[x][y] * scale;
}

__global__ __launch_bounds__(256) void k_g3(const float* __restrict__ PR,
                                            const float* __restrict__ Wv,
                                            float* __restrict__ T) {
  const int m0 = blockIdx.x * 64, n0 = blockIdx.y * 48;
  __shared__ float Ast[16][65];
  __shared__ float Bst[16][49];
  const int t = threadIdx.x;
  const int mi = (t >> 4) * 4, nj = (t & 15) * 3;
  float acc[4][3] = {};
  for (int k0 = 0; k0 < 240; k0 += 16) {
    __syncthreads();
#pragma unroll
    for (int q = 0; q < 4; ++q) {
      int idx = t + q * 256, m = idx >> 4, k = idx & 15;
      Ast[k][m] = PR[(size_t)(m0 + m) * 240 + k0 + k];
    }
#pragma unroll
    for (int q = 0; q < 3; ++q) {
      int idx = t + q * 256, k = idx / 48, n = idx % 48;
      Bst[k][n] = Wv[(size_t)(k0 + k) * 240 + n0 + n];
    }
    __syncthreads();
#pragma unroll
    for (int kk = 0; kk < 16; ++kk) {
      float a4[4], b3[3];
#pragma unroll
      for (int x = 0; x < 4; ++x) a4[x] = Ast[kk][mi + x];
#pragma unroll
      for (int y = 0; y < 3; ++y) b3[y] = Bst[kk][nj + y];
#pragma unroll
      for (int x = 0; x < 4; ++x)
#pragma unroll
        for (int y = 0; y < 3; ++y) acc[x][y] = fmaf(a4[x], b3[y], acc[x][y]);
    }
  }
#pragma unroll
  for (int x = 0; x < 4; ++x)
#pragma unroll
    for (int y = 0; y < 3; ++y)
      T[(size_t)(m0 + mi + x) * 240 + n0 + nj + y] = acc[x][y];
}

__global__ __launch_bounds__(256) void k_g4(const float* __restrict__ Wo,
                                            const float* __restrict__ T,
                                            ushort* __restrict__ W3bf) {
  const int h = blockIdx.x, e0 = blockIdx.y * 64;
  const int b = blockIdx.z / 5, n0 = (blockIdx.z % 5) * 48;
  const float* Bp = T + (size_t)(b * 4 + h) * 30720 + n0;
  ushort* Cp = W3bf + (size_t)b * 491520 + h * 240 + n0;
  __shared__ float Ast[16][65];
  __shared__ float Bst[16][49];
  const int t = threadIdx.x;
  const int mi = (t >> 4) * 4, nj = (t & 15) * 3;
  float acc[4][3] = {};
  for (int k0 = 0; k0 < 128; k0 += 16) {
    __syncthreads();
#pragma unroll
    for (int q = 0; q < 4; ++q) {
      int idx = t + q * 256, m = idx >> 4, k = idx & 15;
      Ast[k][m] = Wo[(size_t)(e0 + m) * 512 + 4 * (k0 + k) + h];
    }
#pragma unroll
    for (int q = 0; q < 3; ++q) {
      int idx = t + q * 256, k = idx / 48, n = idx % 48;
      Bst[k][n] = Bp[(size_t)(k0 + k) * 240 + n];
    }
    __syncthreads();
#pragma unroll
    for (int kk = 0; kk < 16; ++kk) {
      float a4[4], b3[3];
#pragma unroll
      for (int x = 0; x < 4; ++x) a4[x] = Ast[kk][mi + x];
#pragma unroll
      for (int y = 0; y < 3; ++y) b3[y] = Bst[kk][nj + y];
#pragma unroll
      for (int x = 0; x < 4; ++x)
#pragma unroll
        for (int y = 0; y < 3; ++y) acc[x][y] = fmaf(a4[x], b3[y], acc[x][y]);
    }
  }
#pragma unroll
  for (int x = 0; x < 4; ++x)
#pragma unroll
    for (int y = 0; y < 3; ++y)
      Cp[(size_t)(e0 + mi + x) * 960 + nj + y] = f2bf(acc[x][y]);
}

// ---------------------------------------------------------------------------
// InstanceNorm stats + softmax, fused (block-local per bh). grid 32, blk 1024.
// Phase 1: block reduction for mu/rstd; phase 2: 16 waves x 8 rows softmax.
// ---------------------------------------------------------------------------
__global__ __launch_bounds__(1024) void k_inorm(const float* __restrict__ SC,
                                                float* __restrict__ PR) {
  const int bh = blockIdx.x;
  const float* s = SC + (size_t)bh * 30720;
  float* p = PR + (size_t)bh * 30720;
  const int t = threadIdx.x;
  float sum = 0.f, sq = 0.f;
  for (int i = t; i < 30720; i += 1024) {
    float v = s[i];
    sum += v;
    sq = fmaf(v, v, sq);
  }
#pragma unroll
  for (int o = 32; o > 0; o >>= 1) {
    sum += __shfl_down(sum, o);
    sq += __shfl_down(sq, o);
  }
  __shared__ float s1[16], s2[16], bc[2];
  if ((t & 63) == 0) { s1[t >> 6] = sum; s2[t >> 6] = sq; }
  __syncthreads();
  if (t == 0) {
    float ts = 0.f, tq = 0.f;
#pragma unroll
    for (int i = 0; i < 16; ++i) { ts += s1[i]; tq += s2[i]; }
    const float mu = ts * (1.f / 30720.f);
    const float var = tq * (1.f / 30720.f) - mu * mu;
    bc[0] = mu;
    bc[1] = rsqrtf(var + 1e-5f);
  }
  __syncthreads();
  const float mu = bc[0], rstd = bc[1];
  const int wv = t >> 6, l = t & 63;
#pragma unroll
  for (int r = 0; r < 8; ++r) {
    const int row = wv * 8 + r;
    const float* srow = s + (size_t)row * 240;
    float* prow = p + (size_t)row * 240;
    float x0 = (srow[l] - mu) * rstd;
    float x1 = (srow[64 + l] - mu) * rstd;
    float x2 = (srow[128 + l] - mu) * rstd;
    float x3 = (l < 48) ? (srow[192 + l] - mu) * rstd : -1e30f;
    float m = fmaxf(fmaxf(x0, x1), fmaxf(x2, x3));
#pragma unroll
    for (int o = 32; o > 0; o >>= 1) m = fmaxf(m, __shfl_xor(m, o));
    float e0 = __expf(x0 - m), e1 = __expf(x1 - m), e2 = __expf(x2 - m);
    float e3 = (l < 48) ? __expf(x3 - m) : 0.f;
    float ss = e0 + e1 + e2 + e3;
#pragma unroll
    for (int o = 32; o > 0; o >>= 1) ss += __shfl_xor(ss, o);
    const float inv = 1.f / ss;
    prow[l] = e0 * inv;
    prow[64 + l] = e1 * inv;
    prow[128 + l] = e2 * inv;
    if (l < 48) prow[192 + l] = e3 * inv;
  }
}

// ---------------------------------------------------------------------------
// K3 (MFMA, 256x256 tile, 4-buffer depth-3 counted-vmcnt, setprio,
// LDS-bounced coalesced epilogue):
//   O1[b,n,e] = sum_g embaBF[b,n,g] * W3bf[b,e,g]
// grid 256 (1 block/CU), block 512 (8 waves 2x4; wave tile 128x64), BK=32.
// Steady state: vmcnt(8) (2 tiles in flight), one barrier/iter.
// Epilogue: per-wave 16x64 subtiles bounce through private LDS region ->
// 4 fully-coalesced dwordx4 stores per fm (vs 16 scalar).
// ---------------------------------------------------------------------------
__global__ __launch_bounds__(512) void k3_mfma(const ushort* __restrict__ A,
                                               const ushort* __restrict__ Bw,
                                               float* __restrict__ C) {
  __shared__ ushort LDSu[4][16384];  // 128 KB: [buf][A 8192 us | B 8192 us]
  const int bid = blockIdx.x;
  const int swz = (bid & 7) * 32 + (bid >> 3);  // each XCD owns one b
  const int b = swz >> 5;
  const int rem = swz & 31;
  const int mt = rem >> 1, nt = rem & 1;
  const int t = threadIdx.x;
  const int w = t >> 6, l = t & 63;
  const int wr = w >> 2, wc = w & 3;  // wave tile: rows wr*128, cols wc*64

  const ushort* Ab = A + (size_t)b * N_ * KV_ + (size_t)mt * 256 * KV_;
  const ushort* Bb = Bw + (size_t)b * C_ * KV_ + (size_t)nt * 256 * KV_;

  const int r_l = l & 15;        // staging row within 16-row group
  const int c_l = (l >> 4) * 8;  // staging k-chunk (elems)

#define K3STAGE(k0, bf)                                                        \
  do {                                                                         \
    _Pragma("unroll") for (int inst = 0; inst < 2; ++inst) {                   \
      const int g = w * 2 + inst; /* group 0..15 */                            \
      const ushort* ga = Ab + (size_t)(g * 16 + r_l) * KV_ + (k0) + c_l;       \
      __builtin_amdgcn_global_load_lds(                                        \
          (AS1 const uint32_t*)(uintptr_t)ga,                                  \
          (AS3 uint32_t*)(uintptr_t)(&LDSu[bf][0] + g * 512), 16, 0, 0);       \
      const ushort* gb = Bb + (size_t)(g * 16 + r_l) * KV_ + (k0) + c_l;       \
      __builtin_amdgcn_global_load_lds(                                        \
          (AS1 const uint32_t*)(uintptr_t)gb,                                  \
          (AS3 uint32_t*)(uintptr_t)(&LDSu[bf][8192] + g * 512), 16, 0, 0);    \
    }                                                                          \
  } while (0)

  f32x4 acc[8][4];
#pragma unroll
  for (int fm = 0; fm < 8; ++fm)
#pragma unroll
    for (int fn = 0; fn < 4; ++fn) acc[fm][fn] = (f32x4){0.f, 0.f, 0.f, 0.f};

  // prologue: tiles 0,1,2 in flight (12 loads/thread)
  K3STAGE(0, 0);
  K3STAGE(32, 1);
  K3STAGE(64, 2);

  const int NK = KV_ / 32;  // 30
  for (int ks = 0; ks < NK; ++ks) {
    const int nrem = NK - 1 - ks;
    if (nrem >= 2)      asm volatile("s_waitcnt vmcnt(8)" ::: "memory");
    else if (nrem == 1) asm volatile("s_waitcnt vmcnt(4)" ::: "memory");
    else                asm volatile("s_waitcnt vmcnt(0)" ::: "memory");
    __builtin_amdgcn_sched_barrier(0);
    __builtin_amdgcn_s_barrier();
    if (ks + 3 < NK) K3STAGE((ks + 3) * 32, (ks + 3) & 3);
    const int cbuf = ks & 3;
    const ushort* Abase = &LDSu[cbuf][0];
    const ushort* Bbase = &LDSu[cbuf][8192];
    bf16x8 af[8], bv[4];
#pragma unroll
    for (int f = 0; f < 8; ++f)
      af[f] = *(const bf16x8*)(Abase + (wr * 8 + f) * 512 + l * 8);
#pragma unroll
    for (int f = 0; f < 4; ++f)
      bv[f] = *(const bf16x8*)(Bbase + (wc * 4 + f) * 512 + l * 8);
    __builtin_amdgcn_s_setprio(1);
#pragma unroll
    for (int fm = 0; fm < 8; ++fm)
#pragma unroll
      for (int fn = 0; fn < 4; ++fn)
        acc[fm][fn] = __builtin_amdgcn_mfma_f32_16x16x32_bf16(af[fm], bv[fn],
                                                              acc[fm][fn], 0, 0, 0);
    __builtin_amdgcn_s_setprio(0);
  }
#undef K3STAGE

  // ---- epilogue: LDS-bounced coalesced C-write ----
  __builtin_amdgcn_s_barrier();  // all LDS reads of the main loop done
  float* lw = (float*)&LDSu[0][0] + (size_t)w * (16 * 68);  // per-wave [16][68]
  float* Cb = C + (size_t)b * N_ * C_ + ((size_t)mt * 256 + wr * 128) * C_ +
              nt * 256 + wc * 64;
#pragma unroll
  for (int fm = 0; fm < 8; ++fm) {
#pragma unroll
    for (int fn = 0; fn < 4; ++fn)
#pragma unroll
      for (int r = 0; r < 4; ++r)
        lw[((l >> 4) * 4 + r) * 68 + (l & 15) + fn * 16] = acc[fm][fn][r];
#pragma unroll
    for (int q = 0; q < 4; ++q) {
      float4 v = *(const float4*)(lw + (4 * q + (l >> 4)) * 68 + (l & 15) * 4);
      *(float4*)(Cb + (size_t)(fm * 16 + 4 * q + (l >> 4)) * C_ + (l & 15) * 4) = v;
    }
  }
}

// ---------------------------------------------------------------------------
// Memory plan (ws 78,643,200 B + d_out as scratch):
//   d_out [0, 67108864)     P frag-partials (NSPLIT=16, exact fit) -- dead
//                           before k3 overwrites
//   ws [0, 62914560)        embaBF (bf16), written FIRST
//   ws [62914560, 66846720) S (f32) -> then T (f32, after g1)
//   ws [66846720, 70778880) U (f32); W3bf overlays U+SC after both dead
//   ws [70778880, 74711040) SC (f32)
//   ws [74711040, 78643200) PR (f32)
// ---------------------------------------------------------------------------
extern "C" void kernel_launch(void* const* d_in, const int* in_sizes, int n_in,
                              void* d_out, int out_size, void* d_ws, size_t ws_size,
                              hipStream_t stream) {
  const float* emb1 = (const float*)d_in[0];
  const float* emba = (const float*)d_in[1];
  const float* Wq   = (const float*)d_in[2];
  const float* Wk   = (const float*)d_in[3];
  const float* Wv   = (const float*)d_in[4];
  const float* Wo   = (const float*)d_in[5];
  float* out = (float*)d_out;
  char* ws = (char*)d_ws;

  ushort* embaBF = (ushort*)(ws);
  float*  S      = (float*)(ws + 62914560);
  float*  T      = (float*)(ws + 62914560);
  float*  U      = (float*)(ws + 66846720);
  ushort* W3bf   = (ushort*)(ws + 66846720);
  float*  SCb    = (float*)(ws + 70778880);
  float*  PRb    = (float*)(ws + 74711040);
  float*  P      = out;

  // 1) emb_all -> bf16 (feeds k1's B-gather and k3's A)
  k_cvt<<<30720, 256, 0, stream>>>((const float4*)emba, (ushort4*)embaBF, 7864320);

  // 2) S partials (MFMA, 4 blocks/CU) + reduce/unswizzle
  k1_mfma<<<dim3(32, NSPLIT, 2), 512, 0, stream>>>(emb1, embaBF, P);
  k_reduce_frag<<<dim3(32, 32), 256, 0, stream>>>((const f32x4*)P, S);

  // 3) chain (flat-batched f32 GEMMs + fused inorm/softmax)
  k_g1<<<dim3(4, 2, 40), 256, 0, stream>>>(Wq, S, U);
  k_g2<<<dim3(64, 5), 256, 0, stream>>>(U, Wk, SCb);
  k_inorm<<<32, 1024, 0, stream>>>(SCb, PRb);
  k_g3<<<dim3(64, 5), 256, 0, stream>>>(PRb, Wv, T);
  k_g4<<<dim3(4, 8, 40), 256, 0, stream>>>(Wo, T, W3bf);

  // 4) O1[b] = embaBF[b] @ W3bf[b]^T  (MFMA 256^2, depth-3, XCD-swizzled)
  k3_mfma<<<256, 512, 0, stream>>>(embaBF, W3bf, out);
}

// Round 13
// 242.689 us; speedup vs baseline: 1.0163x; 1.0163x over previous
//
#include <hip/hip_runtime.h>
#include <cstdint>
#include <cstddef>

#define B_ 8
#define N_ 4096
#define C_ 512
#define KV_ 960
#define DQ 128
#define DK 240
#define NSPLIT 16  // split-K over n for k1; grid 32*16*2 = 1024 blocks = 4/CU

typedef __attribute__((ext_vector_type(8))) short bf16x8;
typedef __attribute__((ext_vector_type(4))) float f32x4;
#define AS1 __attribute__((address_space(1)))
#define AS3 __attribute__((address_space(3)))

__device__ __forceinline__ ushort f2bf(float f) {
  uint32_t u = __float_as_uint(f);
  u += 0x7FFFu + ((u >> 16) & 1u);  // RNE
  return (ushort)(u >> 16);
}

__device__ __forceinline__ uint32_t cvtpk(float lo, float hi) {
  uint32_t r;
  asm("v_cvt_pk_bf16_f32 %0, %1, %2" : "=v"(r) : "v"(lo), "v"(hi));
  return r;
}

union bfpack {
  uint32_t u[4];
  ushort s[8];
  bf16x8 v;
};

// ---------------------------------------------------------------------------
// K1 (MFMA, gather-staged, 4 blocks/CU, VECTORIZED gathers): partial
//   S[b,h,i,j] = sum_{n in split} emb1[b,n,h*128+i] * embaBF[b,n,h*240+j]
// Change vs R11: A gathered as float2 (col pairs), B as ushort2 -> 16 loads
// per thread per K-step instead of 32 (same coalescing). LDS swizzle
// granularity ((col>>1)&7) on BOTH write and read sides (8-slot spread,
// b128 floor preserved). Thread map: colpair (t&63)*2 x rowgroup t>>6.
// grid (32 bh, NSPLIT, 2 jh), block 512 (8 waves 4x2; wave tile 32x64).
// ---------------------------------------------------------------------------
__global__ __launch_bounds__(512) void k1_mfma(const float* __restrict__ emb1,
                                               const ushort* __restrict__ embaBF,
                                               float* __restrict__ P) {
  __shared__ ushort As[128 * 64];
  __shared__ ushort Bs[128 * 64];
  const int bh = blockIdx.x;
  const int split = blockIdx.y;
  const int jh = blockIdx.z;
  const int b = bh >> 2, h = bh & 3;
  const int t = threadIdx.x;
  const int w = t >> 6, l = t & 63;
  const int wm = w >> 1, wn = w & 1;

  const float* Abase = emb1 + (size_t)b * N_ * C_ + h * DQ;
  const ushort* Bbase = embaBF + (size_t)b * N_ * KV_;

  const int cp2 = (t & 63) * 2;  // col-pair base (0..126)
  const int rg = t >> 6;         // row group 0..7 (8 rows each)
  int jl0 = jh * 128 + cp2;
  if (jl0 > 238) jl0 = 238;      // keep pair in [0,239]; padded cols discarded
  const int jg0 = h * DK + jl0;

  f32x4 acc[2][4];
#pragma unroll
  for (int fm = 0; fm < 2; ++fm)
#pragma unroll
    for (int fn = 0; fn < 4; ++fn) acc[fm][fn] = (f32x4){0.f, 0.f, 0.f, 0.f};

  const int n0 = split * (N_ / NSPLIT);
  const int lrow = l & 15;
  const int KS = (N_ / NSPLIT) / 64;  // 4
  const int swA = (rg ^ ((cp2 >> 1) & 7)) << 3;

  float2 va[8];
  ushort2 ub[8];

  {
    const float* gA = Abase + (size_t)(n0 + rg * 8) * C_ + cp2;
    const ushort* gB = Bbase + (size_t)(n0 + rg * 8) * KV_ + jg0;
#pragma unroll
    for (int kk = 0; kk < 8; ++kk) va[kk] = *(const float2*)(gA + (size_t)kk * C_);
#pragma unroll
    for (int kk = 0; kk < 8; ++kk) ub[kk] = *(const ushort2*)(gB + (size_t)kk * KV_);
  }

  for (int ks = 0; ks < KS; ++ks) {
    bfpack paL, paR, pbL, pbR;
#pragma unroll
    for (int p = 0; p < 4; ++p) {
      paL.u[p] = cvtpk(va[2 * p].x, va[2 * p + 1].x);
      paR.u[p] = cvtpk(va[2 * p].y, va[2 * p + 1].y);
    }
#pragma unroll
    for (int kk = 0; kk < 8; ++kk) { pbL.s[kk] = ub[kk].x; pbR.s[kk] = ub[kk].y; }

    __builtin_amdgcn_s_barrier();

    *(bf16x8*)(As + cp2 * 64 + swA) = paL.v;
    *(bf16x8*)(As + (cp2 + 1) * 64 + swA) = paR.v;
    *(bf16x8*)(Bs + cp2 * 64 + swA) = pbL.v;
    *(bf16x8*)(Bs + (cp2 + 1) * 64 + swA) = pbR.v;

    if (ks + 1 < KS) {
      const int nb1 = n0 + (ks + 1) * 64;
      const float* gA = Abase + (size_t)(nb1 + rg * 8) * C_ + cp2;
      const ushort* gB = Bbase + (size_t)(nb1 + rg * 8) * KV_ + jg0;
#pragma unroll
      for (int kk = 0; kk < 8; ++kk) va[kk] = *(const float2*)(gA + (size_t)kk * C_);
#pragma unroll
      for (int kk = 0; kk < 8; ++kk) ub[kk] = *(const ushort2*)(gB + (size_t)kk * KV_);
    }

    asm volatile("s_waitcnt lgkmcnt(0)" ::: "memory");
    __builtin_amdgcn_sched_barrier(0);
    __builtin_amdgcn_s_barrier();

#pragma unroll
    for (int half = 0; half < 2; ++half) {
      const int kb = half * 4 + (l >> 4);
      bf16x8 af[2], bv[4];
#pragma unroll
      for (int fm = 0; fm < 2; ++fm) {
        const int i = wm * 32 + fm * 16 + lrow;
        af[fm] = *(const bf16x8*)(As + i * 64 + ((kb ^ ((i >> 1) & 7)) << 3));
      }
#pragma unroll
      for (int fn = 0; fn < 4; ++fn) {
        const int j = wn * 64 + fn * 16 + lrow;
        bv[fn] = *(const bf16x8*)(Bs + j * 64 + ((kb ^ ((j >> 1) & 7)) << 3));
      }
#pragma unroll
      for (int fm = 0; fm < 2; ++fm)
#pragma unroll
        for (int fn = 0; fn < 4; ++fn)
          acc[fm][fn] = __builtin_amdgcn_mfma_f32_16x16x32_bf16(af[fm], bv[fn],
                                                                acc[fm][fn], 0, 0, 0);
    }
  }
  f32x4* Pv4 = (f32x4*)P + ((size_t)(split * 32 + bh) * 2 + jh) * 4096;
#pragma unroll
  for (int fm = 0; fm < 2; ++fm)
#pragma unroll
    for (int fn = 0; fn < 4; ++fn) Pv4[(fm * 4 + fn) * 512 + t] = acc[fm][fn];
}

// ---------------------------------------------------------------------------
// Reduce NSPLIT fragment-native partials and un-swizzle into S[bh][128][240].
// ---------------------------------------------------------------------------
__global__ __launch_bounds__(256) void k_reduce_frag(const f32x4* __restrict__ P,
                                                     float* __restrict__ S) {
  const int bh = blockIdx.x;
  const int g = blockIdx.y * 256 + threadIdx.x;
  const int jh = g >> 12;
  const int rest = g & 4095;
  f32x4 a = P[((size_t)bh * 2 + jh) * 4096 + rest];
#pragma unroll
  for (int s = 1; s < NSPLIT; ++s) {
    f32x4 v = P[((size_t)(s * 32 + bh) * 2 + jh) * 4096 + rest];
    a.x += v.x; a.y += v.y; a.z += v.z; a.w += v.w;
  }
  const int v = rest >> 9, tt = rest & 511;
  const int fm = v >> 2, fn = v & 3;
  const int wv = tt >> 6, l = tt & 63;
  const int wm = wv >> 1, wn = wv & 1;
  const int i0 = wm * 32 + fm * 16 + (l >> 4) * 4;
  const int j = jh * 128 + wn * 64 + fn * 16 + (l & 15);
  if (j < DK) {
    float* sp = S + (size_t)bh * (DQ * DK) + (size_t)i0 * DK + j;
    sp[0] = a.x; sp[DK] = a.y; sp[2 * DK] = a.z; sp[3 * DK] = a.w;
  }
}

// ---------------------------------------------------------------------------
// f32 -> bf16 (RNE), 4 elems/thread
// ---------------------------------------------------------------------------
__global__ __launch_bounds__(256) void k_cvt(const float4* __restrict__ in,
                                             ushort4* __restrict__ out, int n4) {
  int i = blockIdx.x * 256 + threadIdx.x;
  if (i >= n4) return;
  float4 v = in[i];
  ushort4 o;
  o.x = f2bf(v.x); o.y = f2bf(v.y); o.z = f2bf(v.z); o.w = f2bf(v.w);
  out[i] = o;
}

// ===========================================================================
// Flat-batched f32 chain GEMMs (unchanged).
// ===========================================================================
__global__ __launch_bounds__(256) void k_g1(const float* __restrict__ Wq,
                                            const float* __restrict__ S,
                                            float* __restrict__ U) {
  const int h = blockIdx.x, c0 = blockIdx.y * 64;
  const int b = blockIdx.z / 5, n0 = (blockIdx.z % 5) * 48;
  const float* A = Wq + (size_t)h * 16384;
  const float* Bp = S + (size_t)(b * 4 + h) * 30720 + n0;
  float* Cp = U + (size_t)(b * 4 + h) * 30720 + n0;
  __shared__ float Ast[16][65];
  __shared__ float Bst[16][49];
  const int t = threadIdx.x;
  const int mi = (t >> 4) * 4, nj = (t & 15) * 3;
  float acc[4][3] = {};
  for (int k0 = 0; k0 < 128; k0 += 16) {
    __syncthreads();
#pragma unroll
    for (int q = 0; q < 4; ++q) {
      int idx = t + q * 256, m = idx >> 4, k = idx & 15;
      Ast[k][m] = A[(size_t)(c0 + m) * 128 + k0 + k];
    }
#pragma unroll
    for (int q = 0; q < 3; ++q) {
      int idx = t + q * 256, k = idx / 48, n = idx % 48;
      Bst[k][n] = Bp[(size_t)(k0 + k) * 240 + n];
    }
    __syncthreads();
#pragma unroll
    for (int kk = 0; kk < 16; ++kk) {
      float a4[4], b3[3];
#pragma unroll
      for (int x = 0; x < 4; ++x) a4[x] = Ast[kk][mi + x];
#pragma unroll
      for (int y = 0; y < 3; ++y) b3[y] = Bst[kk][nj + y];
#pragma unroll
      for (int x = 0; x < 4; ++x)
#pragma unroll
        for (int y = 0; y < 3; ++y) acc[x][y] = fmaf(a4[x], b3[y], acc[x][y]);
    }
  }
#pragma unroll
  for (int x = 0; x < 4; ++x)
#pragma unroll
    for (int y = 0; y < 3; ++y)
      Cp[(size_t)(c0 + mi + x) * 240 + nj + y] = acc[x][y];
}

__global__ __launch_bounds__(256) void k_g2(const float* __restrict__ U,
                                            const float* __restrict__ Wk,
                                            float* __restrict__ SC) {
  const int m0 = blockIdx.x * 64, n0 = blockIdx.y * 48;
  __shared__ float Ast[16][65];
  __shared__ float Bst2[48][17];
  const int t = threadIdx.x;
  const int mi = (t >> 4) * 4, nj = (t & 15) * 3;
  float acc[4][3] = {};
  for (int k0 = 0; k0 < 240; k0 += 16) {
    __syncthreads();
#pragma unroll
    for (int q = 0; q < 4; ++q) {
      int idx = t + q * 256, m = idx >> 4, k = idx & 15;
      Ast[k][m] = U[(size_t)(m0 + m) * 240 + k0 + k];
    }
#pragma unroll
    for (int q = 0; q < 3; ++q) {
      int idx = t + q * 256, n = idx >> 4, kd = idx & 15;
      Bst2[n][kd] = Wk[(size_t)(n0 + n) * 240 + k0 + kd];
    }
    __syncthreads();
#pragma unroll
    for (int kk = 0; kk < 16; ++kk) {
      float a4[4], b3[3];
#pragma unroll
      for (int x = 0; x < 4; ++x) a4[x] = Ast[kk][mi + x];
#pragma unroll
      for (int y = 0; y < 3; ++y) b3[y] = Bst2[nj + y][kk];
#pragma unroll
      for (int x = 0; x < 4; ++x)
#pragma unroll
        for (int y = 0; y < 3; ++y) acc[x][y] = fmaf(a4[x], b3[y], acc[x][y]);
    }
  }
  const float scale = 0.0322748612183951f;
#pragma unroll
  for (int x = 0; x < 4; ++x)
#pragma unroll
    for (int y = 0; y < 3; ++y)
      SC[(size_t)(m0 + mi + x) * 240 + n0 + nj + y] = acc[x][y] * scale;
}

__global__ __launch_bounds__(256) void k_g3(const float* __restrict__ PR,
                                            const float* __restrict__ Wv,
                                            float* __restrict__ T) {
  const int m0 = blockIdx.x * 64, n0 = blockIdx.y * 48;
  __shared__ float Ast[16][65];
  __shared__ float Bst[16][49];
  const int t = threadIdx.x;
  const int mi = (t >> 4) * 4, nj = (t & 15) * 3;
  float acc[4][3] = {};
  for (int k0 = 0; k0 < 240; k0 += 16) {
    __syncthreads();
#pragma unroll
    for (int q = 0; q < 4; ++q) {
      int idx = t + q * 256, m = idx >> 4, k = idx & 15;
      Ast[k][m] = PR[(size_t)(m0 + m) * 240 + k0 + k];
    }
#pragma unroll
    for (int q = 0; q < 3; ++q) {
      int idx = t + q * 256, k = idx / 48, n = idx % 48;
      Bst[k][n] = Wv[(size_t)(k0 + k) * 240 + n0 + n];
    }
    __syncthreads();
#pragma unroll
    for (int kk = 0; kk < 16; ++kk) {
      float a4[4], b3[3];
#pragma unroll
      for (int x = 0; x < 4; ++x) a4[x] = Ast[kk][mi + x];
#pragma unroll
      for (int y = 0; y < 3; ++y) b3[y] = Bst[kk][nj + y];
#pragma unroll
      for (int x = 0; x < 4; ++x)
#pragma unroll
        for (int y = 0; y < 3; ++y) acc[x][y] = fmaf(a4[x], b3[y], acc[x][y]);
    }
  }
#pragma unroll
  for (int x = 0; x < 4; ++x)
#pragma unroll
    for (int y = 0; y < 3; ++y)
      T[(size_t)(m0 + mi + x) * 240 + n0 + nj + y] = acc[x][y];
}

__global__ __launch_bounds__(256) void k_g4(const float* __restrict__ Wo,
                                            const float* __restrict__ T,
                                            ushort* __restrict__ W3bf) {
  const int h = blockIdx.x, e0 = blockIdx.y * 64;
  const int b = blockIdx.z / 5, n0 = (blockIdx.z % 5) * 48;
  const float* Bp = T + (size_t)(b * 4 + h) * 30720 + n0;
  ushort* Cp = W3bf + (size_t)b * 491520 + h * 240 + n0;
  __shared__ float Ast[16][65];
  __shared__ float Bst[16][49];
  const int t = threadIdx.x;
  const int mi = (t >> 4) * 4, nj = (t & 15) * 3;
  float acc[4][3] = {};
  for (int k0 = 0; k0 < 128; k0 += 16) {
    __syncthreads();
#pragma unroll
    for (int q = 0; q < 4; ++q) {
      int idx = t + q * 256, m = idx >> 4, k = idx & 15;
      Ast[k][m] = Wo[(size_t)(e0 + m) * 512 + 4 * (k0 + k) + h];
    }
#pragma unroll
    for (int q = 0; q < 3; ++q) {
      int idx = t + q * 256, k = idx / 48, n = idx % 48;
      Bst[k][n] = Bp[(size_t)(k0 + k) * 240 + n];
    }
    __syncthreads();
#pragma unroll
    for (int kk = 0; kk < 16; ++kk) {
      float a4[4], b3[3];
#pragma unroll
      for (int x = 0; x < 4; ++x) a4[x] = Ast[kk][mi + x];
#pragma unroll
      for (int y = 0; y < 3; ++y) b3[y] = Bst[kk][nj + y];
#pragma unroll
      for (int x = 0; x < 4; ++x)
#pragma unroll
        for (int y = 0; y < 3; ++y) acc[x][y] = fmaf(a4[x], b3[y], acc[x][y]);
    }
  }
#pragma unroll
  for (int x = 0; x < 4; ++x)
#pragma unroll
    for (int y = 0; y < 3; ++y)
      Cp[(size_t)(e0 + mi + x) * 960 + nj + y] = f2bf(acc[x][y]);
}

// ---------------------------------------------------------------------------
// InstanceNorm stats + softmax, fused (block-local per bh). grid 32, blk 1024.
// ---------------------------------------------------------------------------
__global__ __launch_bounds__(1024) void k_inorm(const float* __restrict__ SC,
                                                float* __restrict__ PR) {
  const int bh = blockIdx.x;
  const float* s = SC + (size_t)bh * 30720;
  float* p = PR + (size_t)bh * 30720;
  const int t = threadIdx.x;
  float sum = 0.f, sq = 0.f;
  for (int i = t; i < 30720; i += 1024) {
    float v = s[i];
    sum += v;
    sq = fmaf(v, v, sq);
  }
#pragma unroll
  for (int o = 32; o > 0; o >>= 1) {
    sum += __shfl_down(sum, o);
    sq += __shfl_down(sq, o);
  }
  __shared__ float s1[16], s2[16], bc[2];
  if ((t & 63) == 0) { s1[t >> 6] = sum; s2[t >> 6] = sq; }
  __syncthreads();
  if (t == 0) {
    float ts = 0.f, tq = 0.f;
#pragma unroll
    for (int i = 0; i < 16; ++i) { ts += s1[i]; tq += s2[i]; }
    const float mu = ts * (1.f / 30720.f);
    const float var = tq * (1.f / 30720.f) - mu * mu;
    bc[0] = mu;
    bc[1] = rsqrtf(var + 1e-5f);
  }
  __syncthreads();
  const float mu = bc[0], rstd = bc[1];
  const int wv = t >> 6, l = t & 63;
#pragma unroll
  for (int r = 0; r < 8; ++r) {
    const int row = wv * 8 + r;
    const float* srow = s + (size_t)row * 240;
    float* prow = p + (size_t)row * 240;
    float x0 = (srow[l] - mu) * rstd;
    float x1 = (srow[64 + l] - mu) * rstd;
    float x2 = (srow[128 + l] - mu) * rstd;
    float x3 = (l < 48) ? (srow[192 + l] - mu) * rstd : -1e30f;
    float m = fmaxf(fmaxf(x0, x1), fmaxf(x2, x3));
#pragma unroll
    for (int o = 32; o > 0; o >>= 1) m = fmaxf(m, __shfl_xor(m, o));
    float e0 = __expf(x0 - m), e1 = __expf(x1 - m), e2 = __expf(x2 - m);
    float e3 = (l < 48) ? __expf(x3 - m) : 0.f;
    float ss = e0 + e1 + e2 + e3;
#pragma unroll
    for (int o = 32; o > 0; o >>= 1) ss += __shfl_xor(ss, o);
    const float inv = 1.f / ss;
    prow[l] = e0 * inv;
    prow[64 + l] = e1 * inv;
    prow[128 + l] = e2 * inv;
    if (l < 48) prow[192 + l] = e3 * inv;
  }
}

// ---------------------------------------------------------------------------
// K3 (MFMA, 256x256 tile, 3-buffer counted-vmcnt pipeline, conflict-free):
// exact R11-proven version.
// ---------------------------------------------------------------------------
__global__ __launch_bounds__(512) void k3_mfma(const ushort* __restrict__ A,
                                               const ushort* __restrict__ Bw,
                                               float* __restrict__ C) {
  __shared__ ushort LDSu[3][16384];  // [buf][A 8192 us | B 8192 us]
  const int bid = blockIdx.x;
  const int swz = (bid & 7) * 32 + (bid >> 3);  // each XCD owns one b
  const int b = swz >> 5;
  const int rem = swz & 31;
  const int mt = rem >> 1, nt = rem & 1;
  const int t = threadIdx.x;
  const int w = t >> 6, l = t & 63;
  const int wr = w >> 2, wc = w & 3;  // wave tile: rows wr*128, cols wc*64

  const ushort* Ab = A + (size_t)b * N_ * KV_ + (size_t)mt * 256 * KV_;
  const ushort* Bb = Bw + (size_t)b * C_ * KV_ + (size_t)nt * 256 * KV_;

  const int r_l = l & 15;
  const int c_l = (l >> 4) * 8;

#define K3STAGE(k0, bf)                                                        \
  do {                                                                         \
    _Pragma("unroll") for (int inst = 0; inst < 2; ++inst) {                   \
      const int g = w * 2 + inst;                                              \
      const ushort* ga = Ab + (size_t)(g * 16 + r_l) * KV_ + (k0) + c_l;       \
      __builtin_amdgcn_global_load_lds(                                        \
          (AS1 const uint32_t*)(uintptr_t)ga,                                  \
          (AS3 uint32_t*)(uintptr_t)(&LDSu[bf][0] + g * 512), 16, 0, 0);       \
      const ushort* gb = Bb + (size_t)(g * 16 + r_l) * KV_ + (k0) + c_l;       \
      __builtin_amdgcn_global_load_lds(                                        \
          (AS1 const uint32_t*)(uintptr_t)gb,                                  \
          (AS3 uint32_t*)(uintptr_t)(&LDSu[bf][8192] + g * 512), 16, 0, 0);    \
    }                                                                          \
  } while (0)

  f32x4 acc[8][4];
#pragma unroll
  for (int fm = 0; fm < 8; ++fm)
#pragma unroll
    for (int fn = 0; fn < 4; ++fn) acc[fm][fn] = (f32x4){0.f, 0.f, 0.f, 0.f};

  K3STAGE(0, 0);
  K3STAGE(32, 1);

  const int NK = KV_ / 32;  // 30
  int cbuf = 0, sbuf = 2;
  for (int ks = 0; ks < NK; ++ks) {
    if (ks < NK - 1) asm volatile("s_waitcnt vmcnt(4)" ::: "memory");
    else             asm volatile("s_waitcnt vmcnt(0)" ::: "memory");
    __builtin_amdgcn_sched_barrier(0);
    __builtin_amdgcn_s_barrier();
    if (ks + 2 < NK) K3STAGE((ks + 2) * 32, sbuf);
    const ushort* Abase = &LDSu[cbuf][0];
    const ushort* Bbase = &LDSu[cbuf][8192];
    bf16x8 af[8], bv[4];
#pragma unroll
    for (int f = 0; f < 8; ++f)
      af[f] = *(const bf16x8*)(Abase + (wr * 8 + f) * 512 + l * 8);
#pragma unroll
    for (int f = 0; f < 4; ++f)
      bv[f] = *(const bf16x8*)(Bbase + (wc * 4 + f) * 512 + l * 8);
#pragma unroll
    for (int fm = 0; fm < 8; ++fm)
#pragma unroll
      for (int fn = 0; fn < 4; ++fn)
        acc[fm][fn] = __builtin_amdgcn_mfma_f32_16x16x32_bf16(af[fm], bv[fn],
                                                              acc[fm][fn], 0, 0, 0);
    cbuf = (cbuf == 2) ? 0 : cbuf + 1;
    sbuf = (sbuf == 2) ? 0 : sbuf + 1;
  }
#undef K3STAGE

  float* Cb = C + (size_t)b * N_ * C_ + ((size_t)mt * 256) * C_ + nt * 256;
  const int col = wc * 64 + (l & 15);
  const int rbase = wr * 128 + (l >> 4) * 4;
#pragma unroll
  for (int fm = 0; fm < 8; ++fm)
#pragma unroll
    for (int fn = 0; fn < 4; ++fn)
#pragma unroll
      for (int r = 0; r < 4; ++r)
        Cb[(size_t)(rbase + fm * 16 + r) * C_ + col + fn * 16] = acc[fm][fn][r];
}

// ---------------------------------------------------------------------------
// Memory plan (ws 78,643,200 B + d_out as scratch):
//   d_out [0, 67108864)     P frag-partials (NSPLIT=16) -- dead before k3
//   ws [0, 62914560)        embaBF (bf16), written FIRST
//   ws [62914560, 66846720) S (f32) -> then T (f32, after g1)
//   ws [66846720, 70778880) U (f32); W3bf overlays U+SC after both dead
//   ws [70778880, 74711040) SC (f32)
//   ws [74711040, 78643200) PR (f32)
// ---------------------------------------------------------------------------
extern "C" void kernel_launch(void* const* d_in, const int* in_sizes, int n_in,
                              void* d_out, int out_size, void* d_ws, size_t ws_size,
                              hipStream_t stream) {
  const float* emb1 = (const float*)d_in[0];
  const float* emba = (const float*)d_in[1];
  const float* Wq   = (const float*)d_in[2];
  const float* Wk   = (const float*)d_in[3];
  const float* Wv   = (const float*)d_in[4];
  const float* Wo   = (const float*)d_in[5];
  float* out = (float*)d_out;
  char* ws = (char*)d_ws;

  ushort* embaBF = (ushort*)(ws);
  float*  S      = (float*)(ws + 62914560);
  float*  T      = (float*)(ws + 62914560);
  float*  U      = (float*)(ws + 66846720);
  ushort* W3bf   = (ushort*)(ws + 66846720);
  float*  SCb    = (float*)(ws + 70778880);
  float*  PRb    = (float*)(ws + 74711040);
  float*  P      = out;

  // 1) emb_all -> bf16 (feeds k1's B-gather and k3's A)
  k_cvt<<<30720, 256, 0, stream>>>((const float4*)emba, (ushort4*)embaBF, 7864320);

  // 2) S partials (MFMA, 4 blocks/CU, vectorized gathers) + reduce
  k1_mfma<<<dim3(32, NSPLIT, 2), 512, 0, stream>>>(emb1, embaBF, P);
  k_reduce_frag<<<dim3(32, 32), 256, 0, stream>>>((const f32x4*)P, S);

  // 3) chain (flat-batched f32 GEMMs + fused inorm/softmax)
  k_g1<<<dim3(4, 2, 40), 256, 0, stream>>>(Wq, S, U);
  k_g2<<<dim3(64, 5), 256, 0, stream>>>(U, Wk, SCb);
  k_inorm<<<32, 1024, 0, stream>>>(SCb, PRb);
  k_g3<<<dim3(64, 5), 256, 0, stream>>>(PRb, Wv, T);
  k_g4<<<dim3(4, 8, 40), 256, 0, stream>>>(Wo, T, W3bf);

  // 4) O1[b] = embaBF[b] @ W3bf[b]^T  (MFMA 256^2, R11-proven, XCD-swizzled)
  k3_mfma<<<256, 512, 0, stream>>>(embaBF, W3bf, out);
}